// Round 5
// baseline (60093.506 us; speedup 1.0000x reference)
//
#include <hip/hip_runtime.h>

// MetaLSTMDetector v5: self-timed dataflow (v4 protocol + spill fix + XCD-local
// teams + merged flags).
//
// 64 blocks x 512 thr = 8 teams x 8 members. team = bid&7 -> one team's blocks
// share an XCD under round-robin dispatch (perf heuristic only; correctness is
// agent-scope throughout). Team owns 8 batches; MFMA cols 8-15 duplicate cols
// 0-7 (their outputs are never written). Member owns gate-rows
// [m*128, m*128+128) of both layers; weights live in VGPRs as bf16 A-frags
// (~96 regs; launch_bounds(512,1) so the allocator has >=256 and nothing
// spills -- v4's 40ms was a 128-VGPR cap spilling weights to scratch).
// h0/h1 exchange: global buffers in B-frag layout; producers store packed u32,
// consumers load u64 relaxed agent atomics straight into MFMA B-operands.
// ONE release-flag per wave per step covers both layers' publishes; consumers
// do a single 64-lane __all poll. No LDS, no __syncthreads, no inline asm.
// Schedule per step s: L0[s] (h0[s-1]); L1[s-1] (h0[s-1], h1[s-2]);
// flag=s+1; head[s-2] (member (t&7)==m, wave 0); poll; gather h0[s], h1[s-1].

#define T_LEN 4096

typedef float f32x4  __attribute__((ext_vector_type(4)));
typedef short bf16x8 __attribute__((ext_vector_type(8)));

static __device__ __forceinline__ unsigned int f2bf(float f) {
  unsigned int u = __float_as_uint(f);
  u += 0x7fffu + ((u >> 16) & 1u);   // RNE
  return u >> 16;
}
static __device__ __forceinline__ float bf2f(unsigned short h) {
  return __uint_as_float(((unsigned int)h) << 16);
}
static __device__ __forceinline__ float sigm(float x)  { return 1.0f / (1.0f + __expf(-x)); }
static __device__ __forceinline__ float tanh_(float x) { return 2.0f / (1.0f + __expf(-2.0f * x)) - 1.0f; }

// d_ws poisoned 0xAA each launch; zero the 8 teams x 64 flag words.
// Data buffers need no init: flag-gated, and every byte consumers read is
// written by publishes before the guarding flag.
__global__ void init_ws_kernel(unsigned int* ws) {
  unsigned int i = threadIdx.x;
  if (i < 512u) ws[i] = 0u;
}

__global__ __launch_bounds__(512, 1) void lstm_kernel(
    const float* __restrict__ y,
    const float* __restrict__ Wih0, const float* __restrict__ Whh0,
    const float* __restrict__ bih0, const float* __restrict__ bhh0,
    const float* __restrict__ Wih1, const float* __restrict__ Whh1,
    const float* __restrict__ bih1, const float* __restrict__ bhh1,
    const float* __restrict__ Wout, const float* __restrict__ bout,
    float* __restrict__ out, char* __restrict__ ws)
{
  const int bid  = blockIdx.x;      // 0..63
  const int team = bid & 7;         // 8 teams, XCD-local under round-robin
  const int m    = bid >> 3;        // member 0..7 (M-split)
  const int tid  = threadIdx.x;
  const int w    = tid >> 6;        // wave 0..7
  const int l    = tid & 63;
  const int col  = l & 15;          // MFMA column
  const int c8   = col & 7;         // real batch within team (cols 8-15 dup)
  const int kg   = l >> 4;          // k-group

  // Gate-rows interleaved G[u*4+g]; this wave's 16-row tile: g = base + col.
  const int g = m * 128 + w * 16 + col;
  const int R = (g & 3) * 256 + (g >> 2);        // torch W row: gate*256 + unit
  const int u = m * 32 + w * 4 + kg;             // owned unit (C-frag lane)

  // ---- weight A-fragments (bf16, VGPR-resident; ~100 regs) ----
  bf16x8 a0[8], a1h0[8], a1h1[8], a0x;
  #pragma unroll
  for (int kf = 0; kf < 8; ++kf) {
    bf16x8 v0, v1, v2;
    #pragma unroll
    for (int i = 0; i < 8; ++i) {
      int k = kf * 32 + kg * 8 + i;
      v0[i] = (short)f2bf(Whh0[R * 256 + k]);
      v1[i] = (short)f2bf(Wih1[R * 256 + k]);
      v2[i] = (short)f2bf(Whh1[R * 256 + k]);
    }
    a0[kf] = v0; a1h0[kf] = v1; a1h1[kf] = v2;
  }
  #pragma unroll
  for (int i = 0; i < 8; ++i) a0x[i] = 0;
  if (kg == 0) {
    #pragma unroll
    for (int i = 0; i < 4; ++i) a0x[i] = (short)f2bf(Wih0[R * 4 + i]);
    a0x[4] = (short)f2bf(bih0[R] + bhh0[R]);     // bias0 via x-frag (xf[4]=1)
  }
  float bias1[4];
  #pragma unroll
  for (int r = 0; r < 4; ++r) bias1[r] = bih1[r * 256 + u] + bhh1[r * 256 + u];
  const float bo0 = bout[0], bo1 = bout[1];

  // ---- exchange buffers ----
  unsigned int* flags = (unsigned int*)ws + (size_t)team * 64;   // [8m][8w]
  char* tb = ws + 4096 + (size_t)team * 16384;
  unsigned int*       h0w = (unsigned int*)tb;                   // [2][1024]
  unsigned int*       h1w = (unsigned int*)(tb + 8192);
  unsigned long long* h0q = (unsigned long long*)tb;             // [2][512]
  unsigned long long* h1q = (unsigned long long*)(tb + 8192);
  // frag layout bytes: kf*512 + kg*128 + c8*16 + i*2  (u = kf*32 + kg*8 + i)
  const int pubw = (u >> 5) * 128 + ((u >> 3) & 3) * 32 + c8 * 4 + ((u & 7) >> 1);
  const int ldq  = kg * 16 + c8 * 2;             // u64 units; + kf*64

  const float* yb = y + (size_t)(team * 8 + c8) * T_LEN;
  float* outb = out + (size_t)(team * 8 + c8) * T_LEN * 2;

  bf16x8 f_h0[8], f_h1[8];
  #pragma unroll
  for (int kf = 0; kf < 8; ++kf) {
    #pragma unroll
    for (int i = 0; i < 8; ++i) { f_h0[kf][i] = 0; f_h1[kf][i] = 0; }
  }

  float c0 = 0.f, c1 = 0.f;
  float xw0 = -100.f, xw1 = -100.f, xw2 = -100.f, xw3 = yb[0];
  float yn = yb[1];

  for (int s = 0; s <= T_LEN + 1; ++s) {
    // ---- A: layer 0, h0[s] ----
    if (s < T_LEN) {
      bf16x8 xf;
      #pragma unroll
      for (int i = 0; i < 8; ++i) xf[i] = 0;
      if (kg == 0) {
        xf[0] = (short)f2bf(xw0); xf[1] = (short)f2bf(xw1);
        xf[2] = (short)f2bf(xw2); xf[3] = (short)f2bf(xw3);
        xf[4] = (short)0x3F80;                   // 1.0 (bias lane)
      }
      f32x4 acc = {0.f, 0.f, 0.f, 0.f};
      f32x4 accb = {0.f, 0.f, 0.f, 0.f};
      acc = __builtin_amdgcn_mfma_f32_16x16x32_bf16(a0x, xf, acc, 0, 0, 0);
      #pragma unroll
      for (int kf = 0; kf < 4; ++kf)
        acc = __builtin_amdgcn_mfma_f32_16x16x32_bf16(a0[kf], f_h0[kf], acc, 0, 0, 0);
      #pragma unroll
      for (int kf = 4; kf < 8; ++kf)
        accb = __builtin_amdgcn_mfma_f32_16x16x32_bf16(a0[kf], f_h0[kf], accb, 0, 0, 0);
      float gi = acc[0] + accb[0], gf = acc[1] + accb[1];
      float gg = acc[2] + accb[2], go = acc[3] + accb[3];
      c0 = sigm(gf) * c0 + sigm(gi) * tanh_(gg);
      float h0n = sigm(go) * tanh_(c0);
      unsigned int hv = f2bf(h0n);
      unsigned int hi = __shfl_down(hv, 16, 64);  // partner unit u+1 (kg+1)
      if ((kg & 1) == 0 && col < 8)
        __hip_atomic_store(h0w + (s & 1) * 1024 + pubw, (hv & 0xffffu) | (hi << 16),
                           __ATOMIC_RELAXED, __HIP_MEMORY_SCOPE_AGENT);
    }
    // ---- B: layer 1, h1[s-1] ----
    if (s >= 1 && s <= T_LEN) {
      f32x4 acc  = {bias1[0], bias1[1], bias1[2], bias1[3]};
      f32x4 accb = {0.f, 0.f, 0.f, 0.f};
      #pragma unroll
      for (int kf = 0; kf < 4; ++kf)
        acc = __builtin_amdgcn_mfma_f32_16x16x32_bf16(a1h0[kf], f_h0[kf], acc, 0, 0, 0);
      #pragma unroll
      for (int kf = 4; kf < 8; ++kf)
        accb = __builtin_amdgcn_mfma_f32_16x16x32_bf16(a1h0[kf], f_h0[kf], accb, 0, 0, 0);
      #pragma unroll
      for (int kf = 0; kf < 4; ++kf)
        acc = __builtin_amdgcn_mfma_f32_16x16x32_bf16(a1h1[kf], f_h1[kf], acc, 0, 0, 0);
      #pragma unroll
      for (int kf = 4; kf < 8; ++kf)
        accb = __builtin_amdgcn_mfma_f32_16x16x32_bf16(a1h1[kf], f_h1[kf], accb, 0, 0, 0);
      float gi = acc[0] + accb[0], gf = acc[1] + accb[1];
      float gg = acc[2] + accb[2], go = acc[3] + accb[3];
      c1 = sigm(gf) * c1 + sigm(gi) * tanh_(gg);
      float h1n = sigm(go) * tanh_(c1);
      unsigned int hv = f2bf(h1n);
      unsigned int hi = __shfl_down(hv, 16, 64);
      if ((kg & 1) == 0 && col < 8)
        __hip_atomic_store(h1w + ((s - 1) & 1) * 1024 + pubw, (hv & 0xffffu) | (hi << 16),
                           __ATOMIC_RELAXED, __HIP_MEMORY_SCOPE_AGENT);
    }
    // ---- flag: one release store per wave covers both layers ----
    if (s <= T_LEN && l == 0)
      __hip_atomic_store(&flags[m * 8 + w], (unsigned int)(s + 1),
                         __ATOMIC_RELEASE, __HIP_MEMORY_SCOPE_AGENT);
    // ---- C: head, out[t = s-2] (member (t&7)==m, wave 0; f_h1 = h1[s-2]) ----
    if (s >= 2 && w == 0 && ((s - 2) & 7) == m) {
      int t = s - 2;
      float p0 = 0.f, p1 = 0.f;
      #pragma unroll
      for (int kf = 0; kf < 8; ++kf) {
        #pragma unroll
        for (int i = 0; i < 8; ++i) {
          float hv = bf2f((unsigned short)f_h1[kf][i]);
          int k = kf * 32 + kg * 8 + i;
          p0 += hv * Wout[k];
          p1 += hv * Wout[256 + k];
        }
      }
      p0 += __shfl_xor(p0, 16, 64); p0 += __shfl_xor(p0, 32, 64);
      p1 += __shfl_xor(p1, 16, 64); p1 += __shfl_xor(p1, 32, 64);
      if (kg == 0 && col < 8) {
        float2 o = make_float2(p0 + bo0, p1 + bo1);
        *(float2*)(outb + (size_t)t * 2) = o;
      }
    }
    // ---- D: single merged poll + gathers ----
    if (s <= T_LEN) {
      int tgt = s + 1;
      int v = (int)__hip_atomic_load(&flags[l], __ATOMIC_RELAXED, __HIP_MEMORY_SCOPE_AGENT);
      int it = 0;
      while (!__all(v >= tgt) && ++it < (1 << 22))
        v = (int)__hip_atomic_load(&flags[l], __ATOMIC_RELAXED, __HIP_MEMORY_SCOPE_AGENT);
      if (s <= T_LEN - 1) {          // h0[s] for L0[s+1] / L1[s+1]
        const unsigned long long* src = h0q + (s & 1) * 512 + ldq;
        #pragma unroll
        for (int kf = 0; kf < 8; ++kf) {
          unsigned long long q0 = __hip_atomic_load(src + kf * 64,     __ATOMIC_RELAXED, __HIP_MEMORY_SCOPE_AGENT);
          unsigned long long q1 = __hip_atomic_load(src + kf * 64 + 1, __ATOMIC_RELAXED, __HIP_MEMORY_SCOPE_AGENT);
          union { unsigned long long q[2]; bf16x8 f; } uu;
          uu.q[0] = q0; uu.q[1] = q1;
          f_h0[kf] = uu.f;
        }
      }
      if (s >= 1) {                  // h1[s-1] for L1[s+1] + head[s+1]
        const unsigned long long* src = h1q + ((s - 1) & 1) * 512 + ldq;
        #pragma unroll
        for (int kf = 0; kf < 8; ++kf) {
          unsigned long long q0 = __hip_atomic_load(src + kf * 64,     __ATOMIC_RELAXED, __HIP_MEMORY_SCOPE_AGENT);
          unsigned long long q1 = __hip_atomic_load(src + kf * 64 + 1, __ATOMIC_RELAXED, __HIP_MEMORY_SCOPE_AGENT);
          union { unsigned long long q[2]; bf16x8 f; } uu;
          uu.q[0] = q0; uu.q[1] = q1;
          f_h1[kf] = uu.f;
        }
      }
    }
    // ---- E: slide x window; prefetch y one step ahead ----
    xw0 = xw1; xw1 = xw2; xw2 = xw3; xw3 = yn;
    if (s + 2 < T_LEN) yn = yb[s + 2];
  }
}

extern "C" void kernel_launch(void* const* d_in, const int* in_sizes, int n_in,
                              void* d_out, int out_size, void* d_ws, size_t ws_size,
                              hipStream_t stream) {
  const float* y    = (const float*)d_in[0];
  const float* Wih0 = (const float*)d_in[1];
  const float* Whh0 = (const float*)d_in[2];
  const float* bih0 = (const float*)d_in[3];
  const float* bhh0 = (const float*)d_in[4];
  const float* Wih1 = (const float*)d_in[5];
  const float* Whh1 = (const float*)d_in[6];
  const float* bih1 = (const float*)d_in[7];
  const float* bhh1 = (const float*)d_in[8];
  const float* Wout = (const float*)d_in[9];
  const float* bout = (const float*)d_in[10];

  init_ws_kernel<<<dim3(1), dim3(512), 0, stream>>>((unsigned int*)d_ws);
  lstm_kernel<<<dim3(64), dim3(512), 0, stream>>>(
      y, Wih0, Whh0, bih0, bhh0, Wih1, Whh1, bih1, bhh1, Wout, bout,
      (float*)d_out, (char*)d_ws);
}